// Round 8
// baseline (334.405 us; speedup 1.0000x reference)
//
#include <hip/hip_runtime.h>
#include <math.h>

typedef _Float16 f16;
typedef __attribute__((ext_vector_type(8))) _Float16 f16x8;
typedef __attribute__((ext_vector_type(4))) float    f32x4;
typedef __attribute__((address_space(3))) unsigned int       as3u32;
typedef const __attribute__((address_space(1))) unsigned int as1u32;

constexpr int NB=16, NT=512, NF=256, NMIC=4, NELE=37, NAZI=73;
constexpr int MROWS = NB*NT;     // 8192
constexpr int KDIM  = NF*NMIC;   // 1024
constexpr int NCAND = NELE*NAZI; // 2701
constexpr int NPAD  = 2816;      // padded candidate rows (22*128)
constexpr float SCALE = 2.0f / (float)KDIM;

// unified grid geometry (128x128 tiles)
constexpr int NBT_ROW = MROWS/128;             // 64
constexpr int NBT_COL = NPAD/128;              // 22
constexpr int NBLK_SS = NBT_ROW*NBT_COL;       // 1408
constexpr int NBLK_GR = NBT_COL*(NBT_COL+1)/2; // 253 (triangular incl. diagonal)
constexpr int NBLK    = NBLK_SS + NBLK_GR;     // 1661

constexpr size_t align256(size_t x){ return (x + 255) & ~(size_t)255; }
constexpr size_t G_BYTES = (size_t)NCAND*NCAND*4;          // 29.18 MB
constexpr size_t AHI_OFF = align256(G_BYTES);
constexpr size_t A_BYTES = (size_t)MROWS*KDIM*2;           // 16.78 MB
constexpr size_t ALO_OFF = AHI_OFF + A_BYTES;
constexpr size_t BHI_OFF = ALO_OFF + A_BYTES;
constexpr size_t B_BYTES = (size_t)NPAD*KDIM*2;            // 5.77 MB
constexpr size_t BLO_OFF = BHI_OFF + B_BYTES;
constexpr size_t WS_FAST = BLO_OFF + B_BYTES;              // ~63.9 MB

// ---------------- pre-pass: split f32 -> (hi, lo*2^11) f16 limbs, A and B in one launch ----------------
constexpr int ABLKS = (int)((size_t)MROWS*KDIM/8/256);   // 4096
constexpr int BBLKS = (int)((size_t)NPAD*KDIM/8/256);    // 1408

__global__ __launch_bounds__(256)
void split_combined(const float* __restrict__ srcA, f16* __restrict__ Ahi, f16* __restrict__ Alo,
                    const float* __restrict__ srcB, f16* __restrict__ Bhi, f16* __restrict__ Blo)
{
    long i; const float* src; f16 *hi, *lo; long nsrc;
    if (blockIdx.x < ABLKS) {
        i = ((long)blockIdx.x*256 + threadIdx.x)*8;
        src = srcA; hi = Ahi; lo = Alo; nsrc = (long)MROWS*KDIM;
    } else {
        i = ((long)(blockIdx.x - ABLKS)*256 + threadIdx.x)*8;
        src = srcB; hi = Bhi; lo = Blo; nsrc = (long)NCAND*KDIM;
    }
    f16x8 h, l;
    if (i < nsrc) {
        float4 x0 = *(const float4*)(src + i);
        float4 x1 = *(const float4*)(src + i + 4);
        float xs[8] = {x0.x,x0.y,x0.z,x0.w,x1.x,x1.y,x1.z,x1.w};
        #pragma unroll
        for (int j=0;j<8;++j){
            f16 hh = (f16)xs[j];
            float r = (xs[j] - (float)hh) * 2048.0f;
            h[j] = hh; l[j] = (f16)r;
        }
    } else {
        #pragma unroll
        for (int j=0;j<8;++j){ h[j]=(f16)0.0f; l[j]=(f16)0.0f; }
    }
    *(f16x8*)(hi + i) = h;
    *(f16x8*)(lo + i) = l;
}

// ---------- unified split-f16 MFMA GEMM, wave-tile 64x64 (LDS-intensity 48 FLOP/B) ----------
// Tile 128x128, BK=64 f32-k, 4 waves (2x2), m97 2-barrier structure.
// blocks [0,1408): pred_ss = (A·B^T)*SCALE -> C_ss
// blocks [1408,1661): Gram triangular = (B·B^T) -> G, mirror-write off-diagonal.
// LDS 64 KB -> 2 blocks/CU; VGPR ~215 -> 2 waves/SIMD; 8 waves/CU total.
__global__ __launch_bounds__(256, 2)
void gemm_unified(const f16* __restrict__ Ahi, const f16* __restrict__ Alo,
                  const f16* __restrict__ Bhi, const f16* __restrict__ Blo,
                  float* __restrict__ C_ss, float* __restrict__ G)
{
    __shared__ __align__(16) f16 sAhi[128*64];   // 16 KB each, 64 KB total
    __shared__ __align__(16) f16 sAlo[128*64];
    __shared__ __align__(16) f16 sBhi[128*64];
    __shared__ __align__(16) f16 sBlo[128*64];

    const int tid  = threadIdx.x;
    const int wid  = tid >> 6;
    const int lane = tid & 63;
    const int wr   = wid >> 1;   // 0..1 : 64-row band
    const int wc   = wid & 1;    // 0..1 : 64-col band

    // bijective XCD swizzle (m204) over the full 1D grid
    const int nwg  = gridDim.x;
    const int orig = blockIdx.x;
    const int q = nwg >> 3, r8 = nwg & 7;
    const int xcd = orig & 7, inner = orig >> 3;
    const int wg = (xcd < r8 ? xcd*(q+1) : r8*(q+1) + (xcd-r8)*q) + inner;

    // role
    const f16 *pAhi, *pAlo, *pBhi, *pBlo;
    float* Cp; int row0, col0, Ml; float scale; bool mirror;
    if (wg < NBLK_SS) {
        row0 = (wg / NBT_COL) * 128;
        col0 = (wg % NBT_COL) * 128;
        pAhi = Ahi; pAlo = Alo; pBhi = Bhi; pBlo = Blo;
        Cp = C_ss; Ml = MROWS; scale = SCALE; mirror = false;
    } else {
        int t = wg - NBLK_SS, i = 0;
        #pragma unroll 1
        for (; i < NBT_COL; ++i){ int cnt = NBT_COL - i; if (t < cnt) break; t -= cnt; }
        row0 = i * 128;
        col0 = (i + t) * 128;
        pAhi = Bhi; pAlo = Blo; pBhi = Bhi; pBlo = Blo;
        Cp = G; Ml = NCAND; scale = 1.0f; mirror = (t > 0);   // diagonal: single write (deterministic)
    }

    // staging lane geometry: chunk = 8 rows x 128 B (64 f16); granule swizzle g ^= row&7
    const int lr8 = lane >> 3;        // 0..7 row-in-chunk
    const int lg  = lane & 7;         // dest granule
    const int sg  = lg ^ lr8;         // pre-swizzled source granule

    // ds_read offsets (f16 units), same involution on read
    int aoff[4][2], boff[4][2];
    #pragma unroll
    for (int fi=0; fi<4; ++fi){
        int ra = wr*64 + fi*16 + (lane & 15);
        int rb = wc*64 + fi*16 + (lane & 15);
        #pragma unroll
        for (int ks=0; ks<2; ++ks){
            int g = ks*4 + (lane >> 4);
            aoff[fi][ks] = ra*64 + ((g ^ (ra & 7)) * 8);
            boff[fi][ks] = rb*64 + ((g ^ (rb & 7)) * 8);
        }
    }

    f32x4 acc0[4][4], acc1[4][4];
    #pragma unroll
    for (int i=0;i<4;++i)
        #pragma unroll
        for (int j=0;j<4;++j){
            acc0[i][j] = (f32x4){0.f,0.f,0.f,0.f};
            acc1[i][j] = (f32x4){0.f,0.f,0.f,0.f};
        }

    for (int k0 = 0; k0 < KDIM; k0 += 64) {
        // ---- stage tiles: 16 chunks per array; wave handles chunks j*4+wid (j=0..3)
        #pragma unroll
        for (int j=0; j<4; ++j){
            int c_ = j*4 + wid;
            long soA = (long)(row0 + c_*8 + lr8)*KDIM + k0 + sg*8;
            long soB = (long)(col0 + c_*8 + lr8)*KDIM + k0 + sg*8;
            __builtin_amdgcn_global_load_lds((as1u32*)(pAhi + soA),
                (as3u32*)(sAhi + (size_t)c_*512), 16, 0, 0);
            __builtin_amdgcn_global_load_lds((as1u32*)(pAlo + soA),
                (as3u32*)(sAlo + (size_t)c_*512), 16, 0, 0);
            __builtin_amdgcn_global_load_lds((as1u32*)(pBhi + soB),
                (as3u32*)(sBhi + (size_t)c_*512), 16, 0, 0);
            __builtin_amdgcn_global_load_lds((as1u32*)(pBlo + soB),
                (as3u32*)(sBlo + (size_t)c_*512), 16, 0, 0);
        }
        __syncthreads();   // drains vmcnt; tiles visible

        #pragma unroll
        for (int ks=0; ks<2; ++ks){
            f16x8 ah[4], al[4], bh[4], bl[4];
            #pragma unroll
            for (int fi=0; fi<4; ++fi){
                ah[fi] = *(const f16x8*)(sAhi + aoff[fi][ks]);
                al[fi] = *(const f16x8*)(sAlo + aoff[fi][ks]);
                bh[fi] = *(const f16x8*)(sBhi + boff[fi][ks]);
                bl[fi] = *(const f16x8*)(sBlo + boff[fi][ks]);
            }
            #pragma unroll
            for (int fi=0; fi<4; ++fi)
                #pragma unroll
                for (int fj=0; fj<4; ++fj){
                    acc0[fi][fj] = __builtin_amdgcn_mfma_f32_16x16x32_f16(ah[fi], bh[fj], acc0[fi][fj], 0,0,0);
                    acc1[fi][fj] = __builtin_amdgcn_mfma_f32_16x16x32_f16(ah[fi], bl[fj], acc1[fi][fj], 0,0,0);
                    acc1[fi][fj] = __builtin_amdgcn_mfma_f32_16x16x32_f16(al[fi], bh[fj], acc1[fi][fj], 0,0,0);
                }
        }
        __syncthreads();   // reads done before next-iter staging overwrites
    }

    // epilogue: C/D layout col=lane&15, row=(lane>>4)*4+e; stride NCAND for both outputs
    const float inv2048 = 1.0f/2048.0f;
    #pragma unroll
    for (int fi=0; fi<4; ++fi){
        #pragma unroll
        for (int fj=0; fj<4; ++fj){
            int c = col0 + wc*64 + fj*16 + (lane & 15);
            #pragma unroll
            for (int e=0; e<4; ++e){
                int r = row0 + wr*64 + fi*16 + (lane >> 4)*4 + e;
                if (r < Ml && c < NCAND){
                    float v = (acc0[fi][fj][e] + acc1[fi][fj][e]*inv2048)*scale;
                    Cp[(size_t)r*NCAND + c] = v;
                    if (mirror) Cp[(size_t)c*NCAND + r] = v;
                }
            }
        }
    }
}

// ---------- fallback f32 SGEMM (round-1, known-good) ----------
#define TILE 64
#define BKK  16
#define LDSP 68
__global__ __launch_bounds__(256)
void sgemm_nt_kernel(const float* __restrict__ A, const float* __restrict__ B,
                     float* __restrict__ C, int M, int N, float scale)
{
    __shared__ __align__(16) float As[BKK][LDSP];
    __shared__ __align__(16) float Bs[BKK][LDSP];
    const int tid = threadIdx.x;
    const int tx = tid & 15, ty = tid >> 4;
    const int row0 = blockIdx.y*TILE, col0 = blockIdx.x*TILE;
    const int lm = tid >> 2, lk0 = (tid & 3)*4;
    const int ar = row0 + lm, br = col0 + lm;
    const bool av = (ar < M), bv = (br < N);
    const float* aptr = A + (size_t)(av ? ar : 0)*KDIM + lk0;
    const float* bptr = B + (size_t)(bv ? br : 0)*KDIM + lk0;
    float acc[4][4] = {};
    for (int k0 = 0; k0 < KDIM; k0 += BKK) {
        float4 a4 = av ? *(const float4*)(aptr + k0) : make_float4(0,0,0,0);
        float4 b4 = bv ? *(const float4*)(bptr + k0) : make_float4(0,0,0,0);
        __syncthreads();
        As[lk0+0][lm]=a4.x; As[lk0+1][lm]=a4.y; As[lk0+2][lm]=a4.z; As[lk0+3][lm]=a4.w;
        Bs[lk0+0][lm]=b4.x; Bs[lk0+1][lm]=b4.y; Bs[lk0+2][lm]=b4.z; Bs[lk0+3][lm]=b4.w;
        __syncthreads();
        #pragma unroll
        for (int k=0;k<BKK;++k){
            float4 av4 = *(const float4*)(&As[k][ty*4]);
            float4 bv4 = *(const float4*)(&Bs[k][tx*4]);
            float am[4]={av4.x,av4.y,av4.z,av4.w};
            float bm[4]={bv4.x,bv4.y,bv4.z,bv4.w};
            #pragma unroll
            for (int i=0;i<4;++i)
                #pragma unroll
                for (int j=0;j<4;++j)
                    acc[i][j] = fmaf(am[i], bm[j], acc[i][j]);
        }
    }
    #pragma unroll
    for (int i=0;i<4;++i){
        int r = row0 + ty*4 + i;
        if (r >= M) continue;
        #pragma unroll
        for (int j=0;j<4;++j){
            int c = col0 + tx*4 + j;
            if (c < N) C[(size_t)r*N + c] = acc[i][j]*scale;
        }
    }
}

// ---------- fused IDL argmax: both iterations, ss row kept in registers ----------
__global__ __launch_bounds__(256)
void argmax_fused(const float* __restrict__ ss, const float* __restrict__ G,
                  const float* __restrict__ ele_c, const float* __restrict__ azi_c,
                  float* __restrict__ out_doa, float* __restrict__ out_vad)
{
    const int row  = blockIdx.x*4 + (threadIdx.x >> 6);
    const int lane = threadIdx.x & 63;
    const float* srow = ss + (size_t)row*NCAND;

    float s[43];
    #pragma unroll
    for (int i=0;i<43;++i){
        int c = i*64 + lane;
        s[i] = (c < NCAND) ? srow[c] : -1e30f;
    }

    // ---- iteration 1
    float best = -1e30f; int bi = 0x7fffffff;
    #pragma unroll
    for (int i=0;i<43;++i){
        int c = i*64 + lane;
        if (s[i] > best){ best = s[i]; bi = c; }
    }
    #pragma unroll
    for (int off=32; off; off>>=1){
        float v2 = __shfl_xor(best, off);
        int   i2 = __shfl_xor(bi, off);
        if (v2 > best || (v2 == best && i2 < bi)){ best = v2; bi = i2; }
    }
    float den   = G[(size_t)bi*NCAND + bi];
    float ratio = best / (SCALE*den);
    if (lane == 0){
        int ei = bi / NAZI, ai = bi - ei*NAZI;
        out_doa[(size_t)row*4 + 0] = ele_c[ei];
        out_doa[(size_t)row*4 + 2] = azi_c[ai];
        out_vad[(size_t)row*2 + 0] = ratio;
    }

    // ---- iteration 2: scores2 = s - ratio*SCALE*G[bi, :]
    const float rs = ratio*SCALE;
    const float* grow = G + (size_t)bi*NCAND;
    float best2 = -1e30f; int b2 = 0x7fffffff;
    #pragma unroll
    for (int i=0;i<43;++i){
        int c = i*64 + lane;
        float v = (c < NCAND) ? fmaf(-rs, grow[c], s[i]) : -1e30f;
        if (v > best2){ best2 = v; b2 = c; }
    }
    #pragma unroll
    for (int off=32; off; off>>=1){
        float v2 = __shfl_xor(best2, off);
        int   i2 = __shfl_xor(b2, off);
        if (v2 > best2 || (v2 == best2 && i2 < b2)){ best2 = v2; b2 = i2; }
    }
    if (lane == 0){
        float den2   = G[(size_t)b2*NCAND + b2];
        float ratio2 = best2 / (SCALE*den2);
        int ei = b2 / NAZI, ai = b2 - ei*NAZI;
        out_doa[(size_t)row*4 + 1] = ele_c[ei];
        out_doa[(size_t)row*4 + 3] = azi_c[ai];
        out_vad[(size_t)row*2 + 1] = ratio2;
    }
}

// ---------- launch ----------
extern "C" void kernel_launch(void* const* d_in, const int* in_sizes, int n_in,
                              void* d_out, int out_size, void* d_ws, size_t ws_size,
                              hipStream_t stream)
{
    const float* ipd   = (const float*)d_in[0];   // [8192,1024]
    const float* tmpl  = (const float*)d_in[1];   // [2701,1024]
    const float* ele_c = (const float*)d_in[2];
    const float* azi_c = (const float*)d_in[3];

    float* out     = (float*)d_out;
    float* out_doa = out;                                       // [8192,2,2]
    float* out_vad = out + (size_t)MROWS*4;                     // [8192,2]
    float* out_ss  = out + (size_t)MROWS*4 + (size_t)MROWS*2;   // [8192,2701]

    char*  ws = (char*)d_ws;
    float* G  = (float*)ws;

    dim3 blk256(256);

    if (ws_size >= WS_FAST) {
        f16* Ahi = (f16*)(ws + AHI_OFF);
        f16* Alo = (f16*)(ws + ALO_OFF);
        f16* Bhi = (f16*)(ws + BHI_OFF);
        f16* Blo = (f16*)(ws + BLO_OFF);

        hipLaunchKernelGGL(split_combined, dim3(ABLKS + BBLKS), blk256, 0, stream,
                           ipd, Ahi, Alo, tmpl, Bhi, Blo);

        // pred_ss + triangular Gram in ONE launch (Gram blocks fill the tail)
        hipLaunchKernelGGL(gemm_unified, dim3(NBLK), blk256, 0, stream,
                           Ahi, Alo, Bhi, Blo, out_ss, G);
    } else {
        dim3 g1((NCAND + TILE - 1)/TILE, MROWS/TILE);
        hipLaunchKernelGGL(sgemm_nt_kernel, g1, blk256, 0, stream,
                           ipd, tmpl, out_ss, MROWS, NCAND, SCALE);
        dim3 g2((NCAND + TILE - 1)/TILE, (NCAND + TILE - 1)/TILE);
        hipLaunchKernelGGL(sgemm_nt_kernel, g2, blk256, 0, stream,
                           tmpl, tmpl, G, NCAND, NCAND, 1.0f);
    }

    hipLaunchKernelGGL(argmax_fused, dim3(MROWS/4), blk256, 0, stream,
                       out_ss, G, ele_c, azi_c, out_doa, out_vad);
}

// Round 9
// 328.147 us; speedup vs baseline: 1.0191x; 1.0191x over previous
//
#include <hip/hip_runtime.h>
#include <math.h>

typedef _Float16 f16;
typedef __attribute__((ext_vector_type(8))) _Float16 f16x8;
typedef __attribute__((ext_vector_type(16))) float   f32x16;
typedef __attribute__((address_space(3))) unsigned int       as3u32;
typedef const __attribute__((address_space(1))) unsigned int as1u32;

constexpr int NAZI=73;
constexpr int MROWS = 8192;
constexpr int KDIM  = 1024;
constexpr int NCAND = 2701;
constexpr int NPAD  = 2816;      // padded candidate rows (22*128)
constexpr int GP    = 2704;      // padded Gram row stride (x4B = 16B-aligned rows)
constexpr float SCALE = 2.0f / (float)KDIM;

// unified grid geometry (128x128 tiles); Gram blocks FIRST (they are the long ones)
constexpr int NBT_COL = NPAD/128;              // 22
constexpr int NBLK_SS = (MROWS/128)*NBT_COL;   // 1408
constexpr int NBLK_GR = NBT_COL*(NBT_COL+1)/2; // 253
constexpr int NBLK    = NBLK_SS + NBLK_GR;     // 1661

constexpr size_t align256(size_t x){ return (x + 255) & ~(size_t)255; }
constexpr size_t G_BYTES  = (size_t)NCAND*GP*4;            // 29.2 MB (GP stride)
constexpr size_t A2_OFF   = align256(G_BYTES);
constexpr size_t A2_BYTES = (size_t)MROWS*2048*2;          // 33.55 MB interleaved limbs
constexpr size_t B2_OFF   = A2_OFF + A2_BYTES;
constexpr size_t B2_BYTES = (size_t)NPAD*2048*2;           // 11.53 MB
constexpr size_t WS_FAST  = B2_OFF + B2_BYTES;             // ~74.3 MB

// ---------- pre-pass: split f32 -> interleaved limbs [row][kt(32)][hi 32 f16 | lo 32 f16] ----------
// lo stored UNSCALED (l = x - f16(x)); all limb products share one accumulator downstream.
constexpr int ABLKS = (int)((size_t)MROWS*KDIM/8/256);   // 4096
constexpr int BBLKS = (int)((size_t)NPAD*KDIM/8/256);    // 1408

__global__ __launch_bounds__(256)
void split_combined(const float* __restrict__ srcA, f16* __restrict__ A2,
                    const float* __restrict__ srcB, f16* __restrict__ B2)
{
    int gid; const float* src; f16* dst; int nrows_src, nrows_tot;
    if (blockIdx.x < ABLKS) {
        gid = blockIdx.x*256 + threadIdx.x;
        src = srcA; dst = A2; nrows_src = MROWS; nrows_tot = MROWS;
    } else {
        gid = (blockIdx.x - ABLKS)*256 + threadIdx.x;
        src = srcB; dst = B2; nrows_src = NCAND; nrows_tot = NPAD;
    }
    int m  = gid >> 7;            // 128 granules of 8 f32 per row
    int gi = gid & 127;
    if (m >= nrows_tot) return;
    int kt = gi >> 2, wq = gi & 3;
    long so  = (long)m*1024 + kt*32 + wq*8;
    long dof = (long)m*2048 + kt*64 + wq*8;
    f16x8 h, l;
    if (m < nrows_src) {
        float4 x0 = *(const float4*)(src + so);
        float4 x1 = *(const float4*)(src + so + 4);
        float xs[8] = {x0.x,x0.y,x0.z,x0.w,x1.x,x1.y,x1.z,x1.w};
        #pragma unroll
        for (int j=0;j<8;++j){
            f16 hh = (f16)xs[j];
            l[j] = (f16)(xs[j] - (float)hh);   // unscaled residual
            h[j] = hh;
        }
    } else {
        #pragma unroll
        for (int j=0;j<8;++j){ h[j]=(f16)0.0f; l[j]=(f16)0.0f; }
    }
    *(f16x8*)(dst + dof)      = h;
    *(f16x8*)(dst + dof + 32) = l;
}

// ---------- unified limb-GEMM, 32x32x16 MFMA, merged accumulator ----------
// 128x128 tile, BK=32 f32-k (one 64-f16 interleaved chunk), 4 waves (2x2), wave-tile 64x64.
// m97 2-barrier loop, global_load_lds w=16 (pre-swizzled source), XOR-swizzled ds_read_b128.
// LDS 32 KB -> 3 blocks/CU (R3's proven regime). Gram blocks first; mirror via aligned float4.
__global__ __launch_bounds__(256, 3)
void gemm_unified(const f16* __restrict__ A2, const f16* __restrict__ B2,
                  float* __restrict__ C_ss, float* __restrict__ G)
{
    __shared__ __align__(16) f16 sA[128*64];   // 16 KB
    __shared__ __align__(16) f16 sB[128*64];   // 16 KB

    const int tid  = threadIdx.x;
    const int wid  = tid >> 6;
    const int lane = tid & 63;
    const int wr   = wid >> 1;   // 0..1 : 64-row band
    const int wc   = wid & 1;    // 0..1 : 64-col band

    // bijective XCD swizzle (m204)
    const int nwg  = gridDim.x;
    const int orig = blockIdx.x;
    const int q = nwg >> 3, r8 = nwg & 7;
    const int xcd = orig & 7, inner = orig >> 3;
    const int wg = (xcd < r8 ? xcd*(q+1) : r8*(q+1) + (xcd-r8)*q) + inner;

    // role: Gram triangular blocks first, then pred_ss
    const f16 *pA, *pB; float* Cp; int row0, col0, Ml, ld; float scale; bool mirror;
    if (wg < NBLK_GR) {
        int t = wg, i = 0;
        #pragma unroll 1
        for (; i < NBT_COL; ++i){ int cnt = NBT_COL - i; if (t < cnt) break; t -= cnt; }
        row0 = i*128; col0 = (i + t)*128;
        pA = B2; pB = B2; Cp = G; Ml = NCAND; ld = GP; scale = 1.0f; mirror = (t > 0);
    } else {
        int w2 = wg - NBLK_GR;
        row0 = (w2 / NBT_COL)*128; col0 = (w2 % NBT_COL)*128;
        pA = A2; pB = B2; Cp = C_ss; Ml = MROWS; ld = NCAND; scale = SCALE; mirror = false;
    }

    // staging lane geometry: chunk = 8 rows x 128 B; pre-swizzled source granule
    const int lr8 = lane >> 3;
    const int sg  = (lane & 7) ^ lr8;

    // frag ds_read offsets (f16 units): frag f (32 rows), slice sl (16 f16 of the 64-chunk)
    // granule g = 2*sl + (lane>>5); read swizzle = same involution as staging
    int aoff[2][4], boff[2][4];
    #pragma unroll
    for (int f=0; f<2; ++f){
        int ra = wr*64 + f*32 + (lane & 31);
        int rb = wc*64 + f*32 + (lane & 31);
        #pragma unroll
        for (int sl=0; sl<4; ++sl){
            int g = 2*sl + (lane >> 5);
            aoff[f][sl] = ra*64 + ((g ^ (ra & 7))*8);
            boff[f][sl] = rb*64 + ((g ^ (rb & 7))*8);
        }
    }

    f32x16 acc[2][2];
    #pragma unroll
    for (int i=0;i<2;++i)
        #pragma unroll
        for (int j=0;j<2;++j)
            #pragma unroll
            for (int e=0;e<16;++e) acc[i][j][e] = 0.f;

    for (int kt = 0; kt < 32; ++kt) {
        // stage A,B chunks (16 x 1KB each array; wave handles chunks j*4+wid)
        #pragma unroll
        for (int j=0; j<4; ++j){
            int c_ = j*4 + wid;
            long soA = (long)(row0 + c_*8 + lr8)*2048 + kt*64 + sg*8;
            long soB = (long)(col0 + c_*8 + lr8)*2048 + kt*64 + sg*8;
            __builtin_amdgcn_global_load_lds((as1u32*)(pA + soA),
                (as3u32*)(sA + (size_t)c_*512), 16, 0, 0);
            __builtin_amdgcn_global_load_lds((as1u32*)(pB + soB),
                (as3u32*)(sB + (size_t)c_*512), 16, 0, 0);
        }
        __syncthreads();

        // per f32-k half s: hi slice = s, lo slice = s+2; hh + hl + lh into ONE acc
        #pragma unroll
        for (int s=0; s<2; ++s){
            f16x8 ah[2], al[2], bh[2], bl[2];
            #pragma unroll
            for (int f=0; f<2; ++f){
                ah[f] = *(const f16x8*)(sA + aoff[f][s]);
                al[f] = *(const f16x8*)(sA + aoff[f][s+2]);
                bh[f] = *(const f16x8*)(sB + boff[f][s]);
                bl[f] = *(const f16x8*)(sB + boff[f][s+2]);
            }
            #pragma unroll
            for (int fi=0; fi<2; ++fi)
                #pragma unroll
                for (int fj=0; fj<2; ++fj){
                    acc[fi][fj] = __builtin_amdgcn_mfma_f32_32x32x16_f16(ah[fi], bh[fj], acc[fi][fj], 0,0,0);
                    acc[fi][fj] = __builtin_amdgcn_mfma_f32_32x32x16_f16(ah[fi], bl[fj], acc[fi][fj], 0,0,0);
                    acc[fi][fj] = __builtin_amdgcn_mfma_f32_32x32x16_f16(al[fi], bh[fj], acc[fi][fj], 0,0,0);
                }
        }
        __syncthreads();
    }

    // epilogue: 32x32 C/D layout col=lane&31, row=(reg&3)+8*(reg>>2)+4*(lane>>5)
    #pragma unroll
    for (int fi=0; fi<2; ++fi){
        #pragma unroll
        for (int fj=0; fj<2; ++fj){
            int c = col0 + wc*64 + fj*32 + (lane & 31);
            if (c >= NCAND) continue;
            int rbase = row0 + wr*64 + fi*32 + 4*(lane >> 5);
            #pragma unroll
            for (int qd=0; qd<4; ++qd){
                int r0 = rbase + 8*qd;
                float v0 = acc[fi][fj][4*qd+0]*scale;
                float v1 = acc[fi][fj][4*qd+1]*scale;
                float v2 = acc[fi][fj][4*qd+2]*scale;
                float v3 = acc[fi][fj][4*qd+3]*scale;
                if (r0+0 < Ml) Cp[(size_t)(r0+0)*ld + c] = v0;
                if (r0+1 < Ml) Cp[(size_t)(r0+1)*ld + c] = v1;
                if (r0+2 < Ml) Cp[(size_t)(r0+2)*ld + c] = v2;
                if (r0+3 < Ml) Cp[(size_t)(r0+3)*ld + c] = v3;
                if (mirror) {
                    // off-diagonal Gram: rows r0..r0+3 <= 2687 < NCAND always; 16B-aligned (GP%4==0, r0%4==0)
                    float4 v4 = make_float4(v0, v1, v2, v3);
                    *(float4*)(Cp + (size_t)c*ld + r0) = v4;
                }
            }
        }
    }
}

// ---------- fallback f32 SGEMM (round-1, known-good; ldc parameterized) ----------
#define TILE 64
#define BKK  16
#define LDSP 68
__global__ __launch_bounds__(256)
void sgemm_nt_kernel(const float* __restrict__ A, const float* __restrict__ B,
                     float* __restrict__ C, int M, int N, int ldc, float scale)
{
    __shared__ __align__(16) float As[BKK][LDSP];
    __shared__ __align__(16) float Bs[BKK][LDSP];
    const int tid = threadIdx.x;
    const int tx = tid & 15, ty = tid >> 4;
    const int row0 = blockIdx.y*TILE, col0 = blockIdx.x*TILE;
    const int lm = tid >> 2, lk0 = (tid & 3)*4;
    const int ar = row0 + lm, br = col0 + lm;
    const bool av = (ar < M), bv = (br < N);
    const float* aptr = A + (size_t)(av ? ar : 0)*KDIM + lk0;
    const float* bptr = B + (size_t)(bv ? br : 0)*KDIM + lk0;
    float acc[4][4] = {};
    for (int k0 = 0; k0 < KDIM; k0 += BKK) {
        float4 a4 = av ? *(const float4*)(aptr + k0) : make_float4(0,0,0,0);
        float4 b4 = bv ? *(const float4*)(bptr + k0) : make_float4(0,0,0,0);
        __syncthreads();
        As[lk0+0][lm]=a4.x; As[lk0+1][lm]=a4.y; As[lk0+2][lm]=a4.z; As[lk0+3][lm]=a4.w;
        Bs[lk0+0][lm]=b4.x; Bs[lk0+1][lm]=b4.y; Bs[lk0+2][lm]=b4.z; Bs[lk0+3][lm]=b4.w;
        __syncthreads();
        #pragma unroll
        for (int k=0;k<BKK;++k){
            float4 av4 = *(const float4*)(&As[k][ty*4]);
            float4 bv4 = *(const float4*)(&Bs[k][tx*4]);
            float am[4]={av4.x,av4.y,av4.z,av4.w};
            float bm[4]={bv4.x,bv4.y,bv4.z,bv4.w};
            #pragma unroll
            for (int i=0;i<4;++i)
                #pragma unroll
                for (int j=0;j<4;++j)
                    acc[i][j] = fmaf(am[i], bm[j], acc[i][j]);
        }
    }
    #pragma unroll
    for (int i=0;i<4;++i){
        int r = row0 + ty*4 + i;
        if (r >= M) continue;
        #pragma unroll
        for (int j=0;j<4;++j){
            int c = col0 + tx*4 + j;
            if (c < N) C[(size_t)r*ldc + c] = acc[i][j]*scale;
        }
    }
}

// ---------- fused IDL argmax: both iterations, ss row kept in registers ----------
__global__ __launch_bounds__(256)
void argmax_fused(const float* __restrict__ ss, const float* __restrict__ G,
                  const float* __restrict__ ele_c, const float* __restrict__ azi_c,
                  float* __restrict__ out_doa, float* __restrict__ out_vad)
{
    const int row  = blockIdx.x*4 + (threadIdx.x >> 6);
    const int lane = threadIdx.x & 63;
    const float* srow = ss + (size_t)row*NCAND;

    float s[43];
    #pragma unroll
    for (int i=0;i<43;++i){
        int c = i*64 + lane;
        s[i] = (c < NCAND) ? srow[c] : -1e30f;
    }

    // ---- iteration 1
    float best = -1e30f; int bi = 0x7fffffff;
    #pragma unroll
    for (int i=0;i<43;++i){
        int c = i*64 + lane;
        if (s[i] > best){ best = s[i]; bi = c; }
    }
    #pragma unroll
    for (int off=32; off; off>>=1){
        float v2 = __shfl_xor(best, off);
        int   i2 = __shfl_xor(bi, off);
        if (v2 > best || (v2 == best && i2 < bi)){ best = v2; bi = i2; }
    }
    float den   = G[(size_t)bi*GP + bi];
    float ratio = best / (SCALE*den);
    if (lane == 0){
        int ei = bi / NAZI, ai = bi - ei*NAZI;
        out_doa[(size_t)row*4 + 0] = ele_c[ei];
        out_doa[(size_t)row*4 + 2] = azi_c[ai];
        out_vad[(size_t)row*2 + 0] = ratio;
    }

    // ---- iteration 2: scores2 = s - ratio*SCALE*G[bi, :]
    const float rs = ratio*SCALE;
    const float* grow = G + (size_t)bi*GP;
    float best2 = -1e30f; int b2 = 0x7fffffff;
    #pragma unroll
    for (int i=0;i<43;++i){
        int c = i*64 + lane;
        float v = (c < NCAND) ? fmaf(-rs, grow[c], s[i]) : -1e30f;
        if (v > best2){ best2 = v; b2 = c; }
    }
    #pragma unroll
    for (int off=32; off; off>>=1){
        float v2 = __shfl_xor(best2, off);
        int   i2 = __shfl_xor(b2, off);
        if (v2 > best2 || (v2 == best2 && i2 < b2)){ best2 = v2; b2 = i2; }
    }
    if (lane == 0){
        float den2   = G[(size_t)b2*GP + b2];
        float ratio2 = best2 / (SCALE*den2);
        int ei = b2 / NAZI, ai = b2 - ei*NAZI;
        out_doa[(size_t)row*4 + 1] = ele_c[ei];
        out_doa[(size_t)row*4 + 3] = azi_c[ai];
        out_vad[(size_t)row*2 + 1] = ratio2;
    }
}

// ---------- launch ----------
extern "C" void kernel_launch(void* const* d_in, const int* in_sizes, int n_in,
                              void* d_out, int out_size, void* d_ws, size_t ws_size,
                              hipStream_t stream)
{
    const float* ipd   = (const float*)d_in[0];   // [8192,1024]
    const float* tmpl  = (const float*)d_in[1];   // [2701,1024]
    const float* ele_c = (const float*)d_in[2];
    const float* azi_c = (const float*)d_in[3];

    float* out     = (float*)d_out;
    float* out_doa = out;                                       // [8192,2,2]
    float* out_vad = out + (size_t)MROWS*4;                     // [8192,2]
    float* out_ss  = out + (size_t)MROWS*4 + (size_t)MROWS*2;   // [8192,2701]

    char*  ws = (char*)d_ws;
    float* G  = (float*)ws;                                     // [2701][GP]

    dim3 blk256(256);

    if (ws_size >= WS_FAST) {
        f16* A2 = (f16*)(ws + A2_OFF);
        f16* B2 = (f16*)(ws + B2_OFF);

        hipLaunchKernelGGL(split_combined, dim3(ABLKS + BBLKS), blk256, 0, stream,
                           ipd, A2, tmpl, B2);

        // Gram (triangular, first) + pred_ss in ONE launch
        hipLaunchKernelGGL(gemm_unified, dim3(NBLK), blk256, 0, stream,
                           A2, B2, out_ss, G);
    } else {
        dim3 g1((NCAND + TILE - 1)/TILE, MROWS/TILE);
        hipLaunchKernelGGL(sgemm_nt_kernel, g1, blk256, 0, stream,
                           ipd, tmpl, out_ss, MROWS, NCAND, NCAND, SCALE);
        dim3 g2((NCAND + TILE - 1)/TILE, (NCAND + TILE - 1)/TILE);
        hipLaunchKernelGGL(sgemm_nt_kernel, g2, blk256, 0, stream,
                           tmpl, tmpl, G, NCAND, NCAND, GP, 1.0f);
    }

    hipLaunchKernelGGL(argmax_fused, dim3(MROWS/4), blk256, 0, stream,
                       out_ss, G, ele_c, azi_c, out_doa, out_vad);
}

// Round 10
// 314.009 us; speedup vs baseline: 1.0650x; 1.0450x over previous
//
#include <hip/hip_runtime.h>
#include <math.h>

typedef _Float16 f16;
typedef __attribute__((ext_vector_type(8))) _Float16 f16x8;
typedef __attribute__((ext_vector_type(4))) float    f32x4;
typedef __attribute__((address_space(3))) unsigned int       as3u32;
typedef const __attribute__((address_space(1))) unsigned int as1u32;

constexpr int NAZI=73;
constexpr int MROWS = 8192;
constexpr int KDIM  = 1024;
constexpr int NCAND = 2701;
constexpr int NPAD  = 2816;      // padded candidate rows
constexpr int GP    = 2704;      // padded Gram row stride (16B-aligned rows)
constexpr float SCALE = 2.0f / (float)KDIM;

// unified grid: Gram triangular blocks first (128-row x 64-col tiles), then ss
constexpr int NBT_RI = 22;                    // Gram row tiles (128)
constexpr int NBT_CJ = 44;                    // col tiles (64)
constexpr int NBLK_GR = 506;                  // sum_{i<22} (44-2i)
constexpr int NBLK_SS = (MROWS/128)*NBT_CJ;   // 64*44 = 2816
constexpr int NBLK    = NBLK_GR + NBLK_SS;    // 3322

constexpr size_t align256(size_t x){ return (x + 255) & ~(size_t)255; }
constexpr size_t G_BYTES  = (size_t)NCAND*GP*4;            // 29.2 MB
constexpr size_t A2_OFF   = align256(G_BYTES);
constexpr size_t A2_BYTES = (size_t)MROWS*2048*2;          // 33.55 MB interleaved limbs
constexpr size_t B2_OFF   = A2_OFF + A2_BYTES;
constexpr size_t B2_BYTES = (size_t)NPAD*2048*2;           // 11.53 MB
constexpr size_t WS_FAST  = B2_OFF + B2_BYTES;             // ~74.3 MB

// ---------- pre-pass: split f32 -> interleaved limbs [row][kt(32)][hi 32 f16 | lo 32 f16] ----------
// lo stored UNSCALED (l = x - f16(x)); hh+hl+lh all accumulate into one f32 acc downstream.
constexpr int ABLKS = (int)((size_t)MROWS*KDIM/8/256);   // 4096
constexpr int BBLKS = (int)((size_t)NPAD*KDIM/8/256);    // 1408

__global__ __launch_bounds__(256)
void split_combined(const float* __restrict__ srcA, f16* __restrict__ A2,
                    const float* __restrict__ srcB, f16* __restrict__ B2)
{
    int gid; const float* src; f16* dst; int nrows_src, nrows_tot;
    if (blockIdx.x < ABLKS) {
        gid = blockIdx.x*256 + threadIdx.x;
        src = srcA; dst = A2; nrows_src = MROWS; nrows_tot = MROWS;
    } else {
        gid = (blockIdx.x - ABLKS)*256 + threadIdx.x;
        src = srcB; dst = B2; nrows_src = NCAND; nrows_tot = NPAD;
    }
    int m  = gid >> 7;            // 128 granules of 8 f32 per row
    int gi = gid & 127;
    if (m >= nrows_tot) return;
    int kt = gi >> 2, wq = gi & 3;
    long so  = (long)m*1024 + kt*32 + wq*8;
    long dof = (long)m*2048 + kt*64 + wq*8;
    f16x8 h, l;
    if (m < nrows_src) {
        float4 x0 = *(const float4*)(src + so);
        float4 x1 = *(const float4*)(src + so + 4);
        float xs[8] = {x0.x,x0.y,x0.z,x0.w,x1.x,x1.y,x1.z,x1.w};
        #pragma unroll
        for (int j=0;j<8;++j){
            f16 hh = (f16)xs[j];
            l[j] = (f16)(xs[j] - (float)hh);
            h[j] = hh;
        }
    } else {
        #pragma unroll
        for (int j=0;j<8;++j){ h[j]=(f16)0.0f; l[j]=(f16)0.0f; }
    }
    *(f16x8*)(dst + dof)      = h;
    *(f16x8*)(dst + dof + 32) = l;
}

// ---------- unified limb-GEMM: R3 structure + merged acc, 4 blocks/CU ----------
// Block tile 128x64, BK=32 f32-k (one 64-f16 interleaved chunk), 4 waves (2x2),
// wave-tile 64x32, 16x16x32 MFMA x3 limb products -> ONE f32x4 acc.
// m97 2-barrier loop; global_load_lds w=16 pre-swizzled; R3's proven conflict-free
// 8-granule XOR swizzle. LDS 24 KB; __launch_bounds__(256,4) -> 4 blocks/CU.
__global__ __launch_bounds__(256, 4)
void gemm_unified(const f16* __restrict__ A2, const f16* __restrict__ B2,
                  float* __restrict__ C_ss, float* __restrict__ G)
{
    __shared__ __align__(16) f16 sA[128*64];   // 16 KB
    __shared__ __align__(16) f16 sB[64*64];    //  8 KB

    const int tid  = threadIdx.x;
    const int wid  = tid >> 6;
    const int lane = tid & 63;
    const int wr   = wid >> 1;   // 0..1 : 64-row band
    const int wc   = wid & 1;    // 0..1 : 32-col band

    // bijective XCD swizzle (m204)
    const int nwg  = gridDim.x;
    const int orig = blockIdx.x;
    const int q = nwg >> 3, r8 = nwg & 7;
    const int xcd = orig & 7, inner = orig >> 3;
    const int wg = (xcd < r8 ? xcd*(q+1) : r8*(q+1) + (xcd-r8)*q) + inner;

    // role: Gram triangular first (row tile i:128, col tile j:64, j >= 2i), then ss
    const f16 *pA, *pB; float* Cp; int row0, col0, Ml, ld; float scale; bool mirror;
    if (wg < NBLK_GR) {
        int t = wg, i = 0;
        #pragma unroll 1
        for (; i < NBT_RI; ++i){ int cnt = NBT_CJ - 2*i; if (t < cnt) break; t -= cnt; }
        row0 = i*128; col0 = (2*i + t)*64;
        pA = B2; pB = B2; Cp = G; Ml = NCAND; ld = GP; scale = 1.0f; mirror = true;
    } else {
        int w2 = wg - NBLK_GR;
        row0 = (w2 / NBT_CJ)*128; col0 = (w2 % NBT_CJ)*64;
        pA = A2; pB = B2; Cp = C_ss; Ml = MROWS; ld = NCAND; scale = SCALE; mirror = false;
    }

    // staging lane geometry: unit = 8 rows x 128 B; pre-swizzled source granule
    const int lr8 = lane >> 3;
    const int sg  = (lane & 7) ^ lr8;

    // ds_read offsets (f16 units): granule g hi = (lane>>4), lo = 4+(lane>>4); XOR row&7
    int aofh[4], aofl[4], bofh[2], bofl[2];
    #pragma unroll
    for (int fi=0; fi<4; ++fi){
        int ra = wr*64 + fi*16 + (lane & 15);
        int g  = lane >> 4;
        aofh[fi] = ra*64 + ((g     ^ (ra & 7))*8);
        aofl[fi] = ra*64 + (((4+g) ^ (ra & 7))*8);
    }
    #pragma unroll
    for (int fj=0; fj<2; ++fj){
        int rb = wc*32 + fj*16 + (lane & 15);
        int g  = lane >> 4;
        bofh[fj] = rb*64 + ((g     ^ (rb & 7))*8);
        bofl[fj] = rb*64 + (((4+g) ^ (rb & 7))*8);
    }

    f32x4 acc[4][2];
    #pragma unroll
    for (int i=0;i<4;++i)
        #pragma unroll
        for (int j=0;j<2;++j) acc[i][j] = (f32x4){0.f,0.f,0.f,0.f};

    for (int kt = 0; kt < 32; ++kt) {
        // stage A (16 units, 4/wave) and B (8 units, 2/wave)
        #pragma unroll
        for (int j=0; j<4; ++j){
            int c_ = j*4 + wid;
            long so_ = (long)(row0 + c_*8 + lr8)*2048 + kt*64 + sg*8;
            __builtin_amdgcn_global_load_lds((as1u32*)(pA + so_),
                (as3u32*)(sA + (size_t)c_*512), 16, 0, 0);
        }
        #pragma unroll
        for (int j=0; j<2; ++j){
            int c_ = j*4 + wid;
            long so_ = (long)(col0 + c_*8 + lr8)*2048 + kt*64 + sg*8;
            __builtin_amdgcn_global_load_lds((as1u32*)(pB + so_),
                (as3u32*)(sB + (size_t)c_*512), 16, 0, 0);
        }
        __syncthreads();   // drains vmcnt; tile visible

        f16x8 ah[4], al[4], bh[2], bl[2];
        #pragma unroll
        for (int fi=0; fi<4; ++fi){
            ah[fi] = *(const f16x8*)(sA + aofh[fi]);
            al[fi] = *(const f16x8*)(sA + aofl[fi]);
        }
        #pragma unroll
        for (int fj=0; fj<2; ++fj){
            bh[fj] = *(const f16x8*)(sB + bofh[fj]);
            bl[fj] = *(const f16x8*)(sB + bofl[fj]);
        }
        #pragma unroll
        for (int fi=0; fi<4; ++fi)
            #pragma unroll
            for (int fj=0; fj<2; ++fj){
                acc[fi][fj] = __builtin_amdgcn_mfma_f32_16x16x32_f16(ah[fi], bh[fj], acc[fi][fj], 0,0,0);
                acc[fi][fj] = __builtin_amdgcn_mfma_f32_16x16x32_f16(ah[fi], bl[fj], acc[fi][fj], 0,0,0);
                acc[fi][fj] = __builtin_amdgcn_mfma_f32_16x16x32_f16(al[fi], bh[fj], acc[fi][fj], 0,0,0);
            }
        __syncthreads();   // reads done before next-iter staging overwrites
    }

    // epilogue: 16x16 C/D layout col=lane&15, row=(lane>>4)*4+e
    #pragma unroll
    for (int fi=0; fi<4; ++fi){
        #pragma unroll
        for (int fj=0; fj<2; ++fj){
            int c  = col0 + wc*32 + fj*16 + (lane & 15);
            int r0 = row0 + wr*64 + fi*16 + (lane >> 4)*4;
            float v0 = acc[fi][fj][0]*scale;
            float v1 = acc[fi][fj][1]*scale;
            float v2 = acc[fi][fj][2]*scale;
            float v3 = acc[fi][fj][3]*scale;
            if (c < NCAND){
                if (r0+0 < Ml) Cp[(size_t)(r0+0)*ld + c] = v0;
                if (r0+1 < Ml) Cp[(size_t)(r0+1)*ld + c] = v1;
                if (r0+2 < Ml) Cp[(size_t)(r0+2)*ld + c] = v2;
                if (r0+3 < Ml) Cp[(size_t)(r0+3)*ld + c] = v3;
                // Gram mirror: value bitwise-equal to the transposed tile's direct write
                // (same k-order MFMA), so double-writes are benign & deterministic.
                if (mirror && (r0+3 < NCAND)){
                    float4 v4 = make_float4(v0, v1, v2, v3);
                    *(float4*)(Cp + (size_t)c*ld + r0) = v4;
                }
            }
        }
    }
}

// ---------- fallback f32 SGEMM (round-1, known-good; ldc parameterized) ----------
#define TILE 64
#define BKK  16
#define LDSP 68
__global__ __launch_bounds__(256)
void sgemm_nt_kernel(const float* __restrict__ A, const float* __restrict__ B,
                     float* __restrict__ C, int M, int N, int ldc, float scale)
{
    __shared__ __align__(16) float As[BKK][LDSP];
    __shared__ __align__(16) float Bs[BKK][LDSP];
    const int tid = threadIdx.x;
    const int tx = tid & 15, ty = tid >> 4;
    const int row0 = blockIdx.y*TILE, col0 = blockIdx.x*TILE;
    const int lm = tid >> 2, lk0 = (tid & 3)*4;
    const int ar = row0 + lm, br = col0 + lm;
    const bool av = (ar < M), bv = (br < N);
    const float* aptr = A + (size_t)(av ? ar : 0)*KDIM + lk0;
    const float* bptr = B + (size_t)(bv ? br : 0)*KDIM + lk0;
    float acc[4][4] = {};
    for (int k0 = 0; k0 < KDIM; k0 += BKK) {
        float4 a4 = av ? *(const float4*)(aptr + k0) : make_float4(0,0,0,0);
        float4 b4 = bv ? *(const float4*)(bptr + k0) : make_float4(0,0,0,0);
        __syncthreads();
        As[lk0+0][lm]=a4.x; As[lk0+1][lm]=a4.y; As[lk0+2][lm]=a4.z; As[lk0+3][lm]=a4.w;
        Bs[lk0+0][lm]=b4.x; Bs[lk0+1][lm]=b4.y; Bs[lk0+2][lm]=b4.z; Bs[lk0+3][lm]=b4.w;
        __syncthreads();
        #pragma unroll
        for (int k=0;k<BKK;++k){
            float4 av4 = *(const float4*)(&As[k][ty*4]);
            float4 bv4 = *(const float4*)(&Bs[k][tx*4]);
            float am[4]={av4.x,av4.y,av4.z,av4.w};
            float bm[4]={bv4.x,bv4.y,bv4.z,bv4.w};
            #pragma unroll
            for (int i=0;i<4;++i)
                #pragma unroll
                for (int j=0;j<4;++j)
                    acc[i][j] = fmaf(am[i], bm[j], acc[i][j]);
        }
    }
    #pragma unroll
    for (int i=0;i<4;++i){
        int r = row0 + ty*4 + i;
        if (r >= M) continue;
        #pragma unroll
        for (int j=0;j<4;++j){
            int c = col0 + tx*4 + j;
            if (c < N) C[(size_t)r*ldc + c] = acc[i][j]*scale;
        }
    }
}

// ---------- fused IDL argmax: both iterations, ss row kept in registers ----------
__global__ __launch_bounds__(256)
void argmax_fused(const float* __restrict__ ss, const float* __restrict__ G,
                  const float* __restrict__ ele_c, const float* __restrict__ azi_c,
                  float* __restrict__ out_doa, float* __restrict__ out_vad)
{
    const int row  = blockIdx.x*4 + (threadIdx.x >> 6);
    const int lane = threadIdx.x & 63;
    const float* srow = ss + (size_t)row*NCAND;

    float s[43];
    #pragma unroll
    for (int i=0;i<43;++i){
        int c = i*64 + lane;
        s[i] = (c < NCAND) ? srow[c] : -1e30f;
    }

    // ---- iteration 1
    float best = -1e30f; int bi = 0x7fffffff;
    #pragma unroll
    for (int i=0;i<43;++i){
        int c = i*64 + lane;
        if (s[i] > best){ best = s[i]; bi = c; }
    }
    #pragma unroll
    for (int off=32; off; off>>=1){
        float v2 = __shfl_xor(best, off);
        int   i2 = __shfl_xor(bi, off);
        if (v2 > best || (v2 == best && i2 < bi)){ best = v2; bi = i2; }
    }
    float den   = G[(size_t)bi*GP + bi];
    float ratio = best / (SCALE*den);
    if (lane == 0){
        int ei = bi / NAZI, ai = bi - ei*NAZI;
        out_doa[(size_t)row*4 + 0] = ele_c[ei];
        out_doa[(size_t)row*4 + 2] = azi_c[ai];
        out_vad[(size_t)row*2 + 0] = ratio;
    }

    // ---- iteration 2: scores2 = s - ratio*SCALE*G[bi, :]
    const float rs = ratio*SCALE;
    const float* grow = G + (size_t)bi*GP;
    float best2 = -1e30f; int b2 = 0x7fffffff;
    #pragma unroll
    for (int i=0;i<43;++i){
        int c = i*64 + lane;
        float v = (c < NCAND) ? fmaf(-rs, grow[c], s[i]) : -1e30f;
        if (v > best2){ best2 = v; b2 = c; }
    }
    #pragma unroll
    for (int off=32; off; off>>=1){
        float v2 = __shfl_xor(best2, off);
        int   i2 = __shfl_xor(b2, off);
        if (v2 > best2 || (v2 == best2 && i2 < b2)){ best2 = v2; b2 = i2; }
    }
    if (lane == 0){
        float den2   = G[(size_t)b2*GP + b2];
        float ratio2 = best2 / (SCALE*den2);
        int ei = b2 / NAZI, ai = b2 - ei*NAZI;
        out_doa[(size_t)row*4 + 1] = ele_c[ei];
        out_doa[(size_t)row*4 + 3] = azi_c[ai];
        out_vad[(size_t)row*2 + 1] = ratio2;
    }
}

// ---------- launch ----------
extern "C" void kernel_launch(void* const* d_in, const int* in_sizes, int n_in,
                              void* d_out, int out_size, void* d_ws, size_t ws_size,
                              hipStream_t stream)
{
    const float* ipd   = (const float*)d_in[0];   // [8192,1024]
    const float* tmpl  = (const float*)d_in[1];   // [2701,1024]
    const float* ele_c = (const float*)d_in[2];
    const float* azi_c = (const float*)d_in[3];

    float* out     = (float*)d_out;
    float* out_doa = out;                                       // [8192,2,2]
    float* out_vad = out + (size_t)MROWS*4;                     // [8192,2]
    float* out_ss  = out + (size_t)MROWS*4 + (size_t)MROWS*2;   // [8192,2701]

    char*  ws = (char*)d_ws;
    float* G  = (float*)ws;                                     // [2701][GP]

    dim3 blk256(256);

    if (ws_size >= WS_FAST) {
        f16* A2 = (f16*)(ws + A2_OFF);
        f16* B2 = (f16*)(ws + B2_OFF);

        hipLaunchKernelGGL(split_combined, dim3(ABLKS + BBLKS), blk256, 0, stream,
                           ipd, A2, tmpl, B2);

        // Gram (triangular, first) + pred_ss in ONE launch
        hipLaunchKernelGGL(gemm_unified, dim3(NBLK), blk256, 0, stream,
                           A2, B2, out_ss, G);
    } else {
        dim3 g1((NCAND + TILE - 1)/TILE, MROWS/TILE);
        hipLaunchKernelGGL(sgemm_nt_kernel, g1, blk256, 0, stream,
                           ipd, tmpl, out_ss, MROWS, NCAND, NCAND, SCALE);
        dim3 g2((NCAND + TILE - 1)/TILE, (NCAND + TILE - 1)/TILE);
        hipLaunchKernelGGL(sgemm_nt_kernel, g2, blk256, 0, stream,
                           tmpl, tmpl, G, NCAND, NCAND, GP, 1.0f);
    }

    hipLaunchKernelGGL(argmax_fused, dim3(MROWS/4), blk256, 0, stream,
                       out_ss, G, ele_c, azi_c, out_doa, out_vad);
}